// Round 3
// baseline (219.383 us; speedup 1.0000x reference)
//
#include <hip/hip_runtime.h>

// MHAttention B=8 T=2048 C=512 H=512, causal, fp32 in/out.
// cast(fp32->fp16) -> fused QKV GEMM (Q,K row-major; V transposed) -> flash.
// R3: flash restructured: batch->XCD swizzle (K_b+V_b = 4MB fits one XCD L2),
// KVBLK=64 with K-only LDS dbuf, V read direct from L2 as PV B-frags,
// full-D QK per wave (no partial-sum round-trip), in-register online softmax,
// 3 barriers per 64-kv iter (2 lgkm-only).

using short8 = __attribute__((ext_vector_type(8))) short;
using half8  = __attribute__((ext_vector_type(8))) _Float16;
using f32x4  = __attribute__((ext_vector_type(4))) float;

#define B_    8
#define T_    2048
#define SCALE_ 0.044194173824159216f   // 512^-0.5

// flash dynamic LDS layout
#define FL_P    131072   // [32 q][64 kv] f16, 16B-chunk XOR swizzle (chunk ^= row&7)
#define FL_STX  135168   // [32 row][4 sc] f32 tile-max partials
#define FL_STS  135680   // [32 row][4 sc] f32 tile-sum partials
#define FL_RM   136192   // [32] f32 running max
#define FL_SMEM 136320

__device__ __forceinline__ void gload_lds16(const void* g, void* l) {
  __builtin_amdgcn_global_load_lds(
      (const __attribute__((address_space(1))) unsigned int*)g,
      (__attribute__((address_space(3))) unsigned int*)l, 16, 0, 0);
}

__device__ __forceinline__ unsigned short f2h(float f) {  // RNE f32->f16 bits
  _Float16 h = (_Float16)f;
  return *(unsigned short*)&h;
}

// barrier waiting only on LDS ops — keeps global_load_lds prefetch (vmcnt) in flight
__device__ __forceinline__ void barrier_lgkm() {
  asm volatile("s_waitcnt lgkmcnt(0)" ::: "memory");
  __builtin_amdgcn_s_barrier();
  asm volatile("" ::: "memory");
}

// ---------------------------------------------------------------- cast kernel
__global__ __launch_bounds__(256) void cast_kernel(
    const float* __restrict__ x, const float* __restrict__ wq,
    const float* __restrict__ wk, const float* __restrict__ wv,
    unsigned short* __restrict__ xb, unsigned short* __restrict__ wcat) {
  size_t i4 = (size_t)blockIdx.x * 256 + threadIdx.x;   // one float4 per thread
  const size_t NX4 = (size_t)(B_ * T_ * 512) / 4;       // 2097152
  const float* src; unsigned short* dst; size_t off4;
  if (i4 < NX4) { src = x; dst = xb; off4 = i4; }
  else {
    size_t w4 = i4 - NX4;                 // < 196608
    size_t mat = w4 >> 16;                // 65536 float4 per 512x512 matrix
    off4 = w4 & 65535;
    src = (mat == 0) ? wq : (mat == 1) ? wk : wv;
    dst = wcat + (mat << 18);
  }
  float4 v = ((const float4*)src)[off4];
  unsigned long long pk = (unsigned long long)f2h(v.x)
                        | ((unsigned long long)f2h(v.y) << 16)
                        | ((unsigned long long)f2h(v.z) << 32)
                        | ((unsigned long long)f2h(v.w) << 48);
  *(unsigned long long*)(dst + off4 * 4) = pk;
}

// ---------------------------------------------------------------- QKV GEMM
// C[m][n] = sum_k xb[m][k] * wcat[n][k],  M=16384, N=1536, K=512.
// 128x128 tile, BK=64, 4 waves (2x2), 16x16x32 f16 MFMA, double-buffered LDS.
// Grid (128 m-panels, 12 n): linear id = n*128 + m -> XCD = m%8, so all 12
// n-blocks of an m-panel share one XCD L2 (A-panel fetched from HBM once).
__device__ __forceinline__ void gemm_stage(
    const unsigned short* __restrict__ xb, const unsigned short* __restrict__ wcat,
    char* smem, int buf, int mbase, int nbase, int kt, int wv, int lane, int srcg) {
  char* base = smem + buf * 32768;
  const int kbase = kt * 64;
  if (wv < 2) {
    #pragma unroll
    for (int i = 0; i < 8; ++i) {
      const int blk = wv * 8 + i;
      const int row = blk * 8 + (lane >> 3);
      gload_lds16(xb + (size_t)(mbase + row) * 512 + kbase + srcg, base + blk * 1024);
    }
  } else {
    #pragma unroll
    for (int i = 0; i < 8; ++i) {
      const int blk = (wv - 2) * 8 + i;
      const int row = blk * 8 + (lane >> 3);
      gload_lds16(wcat + (size_t)(nbase + row) * 512 + kbase + srcg, base + 16384 + blk * 1024);
    }
  }
}

__global__ __launch_bounds__(256, 2) void gemm_qkv(
    const unsigned short* __restrict__ xb, const unsigned short* __restrict__ wcat,
    unsigned short* __restrict__ Qb, unsigned short* __restrict__ Kb,
    unsigned short* __restrict__ Vtb) {
  __shared__ char smem[65536];
  const int tid = threadIdx.x, lane = tid & 63, wv = tid >> 6;
  const int wr = wv >> 1, wc = wv & 1;
  const int l15 = lane & 15, l4 = lane >> 4;
  const int mbase = blockIdx.x * 128;
  const int nbase = blockIdx.y * 128;
  const int srcg = (((lane & 7) ^ ((lane >> 3) & 7))) * 8;

  f32x4 acc[4][4];
  #pragma unroll
  for (int i = 0; i < 4; ++i)
    #pragma unroll
    for (int j = 0; j < 4; ++j) acc[i][j] = (f32x4){0.f, 0.f, 0.f, 0.f};

  gemm_stage(xb, wcat, smem, 0, mbase, nbase, 0, wv, lane, srcg);
  for (int kt = 0; kt < 8; ++kt) {
    __syncthreads();
    if (kt < 7) gemm_stage(xb, wcat, smem, (kt + 1) & 1, mbase, nbase, kt + 1, wv, lane, srcg);
    const char* base = smem + (kt & 1) * 32768;
    #pragma unroll
    for (int ks = 0; ks < 2; ++ks) {
      half8 a[4], b8[4];
      #pragma unroll
      for (int rt = 0; rt < 4; ++rt) {
        const int row = wr * 64 + rt * 16 + l15;
        const int G = (ks * 4 + l4) ^ (row & 7);
        a[rt] = *(const half8*)(base + row * 128 + G * 16);
      }
      #pragma unroll
      for (int ct = 0; ct < 4; ++ct) {
        const int row = wc * 64 + ct * 16 + l15;
        const int G = (ks * 4 + l4) ^ (row & 7);
        b8[ct] = *(const half8*)(base + 16384 + row * 128 + G * 16);
      }
      #pragma unroll
      for (int rt = 0; rt < 4; ++rt)
        #pragma unroll
        for (int ct = 0; ct < 4; ++ct)
          acc[rt][ct] = __builtin_amdgcn_mfma_f32_16x16x32_f16(a[rt], b8[ct], acc[rt][ct], 0, 0, 0);
    }
  }

  const int mat = nbase >> 9;          // 0=Q, 1=K, 2=V
  const int nloc = nbase & 511;
  if (mat < 2) {
    unsigned short* O = (mat == 0) ? Qb : Kb;
    #pragma unroll
    for (int rt = 0; rt < 4; ++rt)
      #pragma unroll
      for (int ct = 0; ct < 4; ++ct) {
        const int m0 = mbase + wr * 64 + rt * 16 + l4 * 4;
        const int n = nloc + wc * 64 + ct * 16 + l15;
        #pragma unroll
        for (int j = 0; j < 4; ++j)
          O[(size_t)(m0 + j) * 512 + n] = f2h(acc[rt][ct][j]);
      }
  } else {
    #pragma unroll
    for (int rt = 0; rt < 4; ++rt)
      #pragma unroll
      for (int ct = 0; ct < 4; ++ct) {
        const int m0 = mbase + wr * 64 + rt * 16 + l4 * 4;
        const int d = nloc + wc * 64 + ct * 16 + l15;
        const int bb = m0 >> 11, t = m0 & 2047;
        unsigned long long pk = (unsigned long long)f2h(acc[rt][ct][0])
                              | ((unsigned long long)f2h(acc[rt][ct][1]) << 16)
                              | ((unsigned long long)f2h(acc[rt][ct][2]) << 32)
                              | ((unsigned long long)f2h(acc[rt][ct][3]) << 48);
        *(unsigned long long*)(Vtb + ((size_t)bb * 512 + d) * 2048 + t) = pk;
      }
  }
}

// ---------------------------------------------------------------- flash attention
// 256 WGs x 8 waves; b = blk&7 (-> XCD b), pair = blk>>3; passes {pair, 63-pair}
// of 32 q-rows (balanced: 33-34 KVBLK=64 iters per WG).
// QK role: wave (sr=wv>>2, sc=wv&3) computes S-tile [sr*16..+16)x[sc*16..+16)
//   over FULL D=512 (16 MFMA, 2 acc chains) from K LDS (dbuf, XOR-swizzled).
// PV role: wave wv owns d in [wv*64..+64); V frags loaded direct from global (L2).
// Per iter: syncthreads(A: K staged) -> QK+tilemax -> lgkm(B) -> softmax in-reg,
//   P+stats to LDS -> lgkm(C) -> rescale+PV. m/alpha/l carried in registers.
__device__ __forceinline__ void stage_k(const unsigned short* __restrict__ Kb,
                                        char* smem, int buf, size_t bT, int kvt,
                                        int wv, int lane) {
  char* dst = smem + buf * 65536;
  const unsigned short* src = Kb + (bT + (size_t)kvt * 64) * 512;
  #pragma unroll
  for (int i = 0; i < 8; ++i) {
    const int r = wv * 8 + i;                       // 64 rows x 1KB
    gload_lds16(src + (size_t)r * 512 + ((lane ^ (r & 7)) * 8), dst + r * 1024);
  }
}

__global__ __launch_bounds__(512, 2) void flash_kernel(
    const unsigned short* __restrict__ Qb, const unsigned short* __restrict__ Kb,
    const unsigned short* __restrict__ Vtb, float* __restrict__ out) {
  extern __shared__ char smem[];
  float* stx  = (float*)(smem + FL_STX);
  float* sts  = (float*)(smem + FL_STS);
  float* rowm = (float*)(smem + FL_RM);

  const int tid = threadIdx.x, lane = tid & 63, wv = tid >> 6;
  const int sr = wv >> 2, sc = wv & 3;
  const int l15 = lane & 15, l4 = lane >> 4;
  const int b = blockIdx.x & 7;                     // batch == XCD
  const int pair = blockIdx.x >> 3;
  const size_t bT = (size_t)b * T_;

  for (int pass = 0; pass < 2; ++pass) {
    const int qt = pass ? (63 - pair) : pair;       // 32-row q-tile index
    const int nkv = (qt + 2) >> 1;                  // # 64-wide kv tiles
    __syncthreads();                                // prev pass done with LDS
    if (tid < 32) rowm[tid] = -1e30f;

    half8 qf[16];                                   // Q row sr*16+l15, full D
    {
      const unsigned short* qp = Qb + (bT + qt * 32 + sr * 16 + l15) * 512 + l4 * 8;
      #pragma unroll
      for (int ks = 0; ks < 16; ++ks) qf[ks] = *(const half8*)(qp + ks * 32);
    }
    f32x4 o[2][4];
    float lreg[2][4], mold_pv[2][4], mold_qk[4];
    #pragma unroll
    for (int mt = 0; mt < 2; ++mt)
      #pragma unroll
      for (int j = 0; j < 4; ++j) {
        o[mt][j] = (f32x4){0.f, 0.f, 0.f, 0.f};     // o[mt][dt] zero (dt==j loop below reuses)
        lreg[mt][j] = 0.f; mold_pv[mt][j] = -1e30f;
      }
    #pragma unroll
    for (int dt = 0; dt < 4; ++dt) { o[0][dt] = (f32x4){0.f,0.f,0.f,0.f}; o[1][dt] = (f32x4){0.f,0.f,0.f,0.f}; }
    #pragma unroll
    for (int j = 0; j < 4; ++j) mold_qk[j] = -1e30f;

    stage_k(Kb, smem, 0, bT, 0, wv, lane);

    for (int kv = 0; kv < nkv; ++kv) {
      const int buf = kv & 1;
      const int kv0 = kv * 64;
      __syncthreads();                              // A: K tile ready (vmcnt drained)

      // V B-frags for this tile, direct from global (L2-resident, read once/WG)
      half8 vf[4][2];
      #pragma unroll
      for (int dt = 0; dt < 4; ++dt) {
        const unsigned short* vp =
            Vtb + ((size_t)b * 512 + wv * 64 + dt * 16 + l15) * 2048 + kv0 + l4 * 8;
        vf[dt][0] = *(const half8*)(vp);
        vf[dt][1] = *(const half8*)(vp + 32);
      }
      if (kv + 1 < nkv) stage_k(Kb, smem, buf ^ 1, bT, kv + 1, wv, lane);

      // ---- QK^T full-D, 2 accumulation chains ----
      f32x4 s0 = (f32x4){0.f,0.f,0.f,0.f}, s1 = (f32x4){0.f,0.f,0.f,0.f};
      {
        const char* kb = smem + buf * 65536;
        const int krow = sc * 16 + l15;
        const int rsw = krow & 7;
        #pragma unroll
        for (int ks = 0; ks < 16; ks += 2) {
          half8 k0 = *(const half8*)(kb + krow * 1024 + ((ks * 4 + l4) ^ rsw) * 16);
          half8 k1 = *(const half8*)(kb + krow * 1024 + (((ks + 1) * 4 + l4) ^ rsw) * 16);
          s0 = __builtin_amdgcn_mfma_f32_16x16x32_f16(qf[ks], k0, s0, 0, 0, 0);
          s1 = __builtin_amdgcn_mfma_f32_16x16x32_f16(qf[ks + 1], k1, s1, 0, 0, 0);
        }
      }
      // scale + causal mask + per-row tile-max (16-lane shuffle)
      float v[4], tm[4];
      const int kg = kv0 + sc * 16 + l15;
      #pragma unroll
      for (int j = 0; j < 4; ++j) {
        const int qg = qt * 32 + sr * 16 + l4 * 4 + j;
        const float sv = (s0[j] + s1[j]) * SCALE_;
        v[j] = (kg <= qg) ? sv : -1e30f;
        tm[j] = v[j];
      }
      #pragma unroll
      for (int m = 1; m < 16; m <<= 1)
        #pragma unroll
        for (int j = 0; j < 4; ++j) tm[j] = fmaxf(tm[j], __shfl_xor(tm[j], m, 64));
      if (l15 == 0) {
        #pragma unroll
        for (int j = 0; j < 4; ++j) stx[(sr * 16 + l4 * 4 + j) * 4 + sc] = tm[j];
      }
      barrier_lgkm();                               // B: tile maxes visible

      // ---- softmax (in-register running max) ----
      float mnewv[4], pr[4]; unsigned short ph[4];
      #pragma unroll
      for (int j = 0; j < 4; ++j) {
        const int r = sr * 16 + l4 * 4 + j;
        f32x4 sx = *(const f32x4*)(stx + r * 4);
        const float mn = fmaxf(fmaxf(fmaxf(sx[0], sx[1]), fmaxf(sx[2], sx[3])), mold_qk[j]);
        mnewv[j] = mn; mold_qk[j] = mn;
        const float p = __expf(v[j] - mn);
        ph[j] = f2h(p);                             // round first; sum the rounded
        pr[j] = (float)*(const _Float16*)&ph[j];
      }
      float ps[4];
      #pragma unroll
      for (int j = 0; j < 4; ++j) ps[j] = pr[j];
      #pragma unroll
      for (int m = 1; m < 16; m <<= 1)
        #pragma unroll
        for (int j = 0; j < 4; ++j) ps[j] += __shfl_xor(ps[j], m, 64);
      if (l15 == 0) {
        #pragma unroll
        for (int j = 0; j < 4; ++j) {
          const int r = sr * 16 + l4 * 4 + j;
          sts[r * 4 + sc] = ps[j];
          if (sc == 0) rowm[r] = mnewv[j];
        }
      }
      #pragma unroll
      for (int j = 0; j < 4; ++j) {                 // P -> LDS (chunk-XOR swizzle)
        const int r = sr * 16 + l4 * 4 + j;
        const int c = sc * 16 + l15;
        *(unsigned short*)(smem + FL_P + r * 128 + (((c >> 3) ^ (r & 7)) * 16) + (c & 7) * 2) = ph[j];
      }
      barrier_lgkm();                               // C: P + sums + rowm visible

      // ---- rescale O + update l, then PV ----
      float al[2][4];
      #pragma unroll
      for (int mt = 0; mt < 2; ++mt)
        #pragma unroll
        for (int j = 0; j < 4; ++j) {
          const int r = mt * 16 + l4 * 4 + j;
          const float mn = rowm[r];
          const float a = __expf(mold_pv[mt][j] - mn);
          mold_pv[mt][j] = mn;
          f32x4 s4 = *(const f32x4*)(sts + r * 4);
          lreg[mt][j] = a * lreg[mt][j] + ((s4[0] + s4[1]) + (s4[2] + s4[3]));
          al[mt][j] = a;
        }
      #pragma unroll
      for (int mt = 0; mt < 2; ++mt)
        #pragma unroll
        for (int dt = 0; dt < 4; ++dt)
          #pragma unroll
          for (int j = 0; j < 4; ++j) o[mt][dt][j] *= al[mt][j];
      half8 pa[2][2];
      #pragma unroll
      for (int mt = 0; mt < 2; ++mt) {
        const int row = mt * 16 + l15;
        #pragma unroll
        for (int k2 = 0; k2 < 2; ++k2)
          pa[mt][k2] = *(const half8*)(smem + FL_P + row * 128 + (((k2 * 4 + l4) ^ (row & 7)) * 16));
      }
      #pragma unroll
      for (int dt = 0; dt < 4; ++dt)
        #pragma unroll
        for (int mt = 0; mt < 2; ++mt) {
          o[mt][dt] = __builtin_amdgcn_mfma_f32_16x16x32_f16(pa[mt][0], vf[dt][0], o[mt][dt], 0, 0, 0);
          o[mt][dt] = __builtin_amdgcn_mfma_f32_16x16x32_f16(pa[mt][1], vf[dt][1], o[mt][dt], 0, 0, 0);
        }
    }

    // ---- epilogue: out = O / l (all state in registers) ----
    #pragma unroll
    for (int mt = 0; mt < 2; ++mt) {
      float li[4];
      #pragma unroll
      for (int j = 0; j < 4; ++j) li[j] = 1.0f / lreg[mt][j];
      #pragma unroll
      for (int dt = 0; dt < 4; ++dt)
        #pragma unroll
        for (int j = 0; j < 4; ++j)
          out[(bT + qt * 32 + mt * 16 + l4 * 4 + j) * 512 + wv * 64 + dt * 16 + l15] =
              o[mt][dt][j] * li[j];
    }
  }
}

// ---------------------------------------------------------------- launch
extern "C" void kernel_launch(void* const* d_in, const int* in_sizes, int n_in,
                              void* d_out, int out_size, void* d_ws, size_t ws_size,
                              hipStream_t stream) {
  (void)in_sizes; (void)n_in; (void)out_size; (void)ws_size;
  const float* x  = (const float*)d_in[0];
  const float* wq = (const float*)d_in[1];
  const float* wk = (const float*)d_in[2];
  const float* wv = (const float*)d_in[3];
  float* out = (float*)d_out;

  unsigned short* ws   = (unsigned short*)d_ws;
  unsigned short* xb   = ws;                                    // [16384][512]
  unsigned short* wcat = xb + (size_t)16384 * 512;              // [1536][512]
  unsigned short* Qb   = wcat + (size_t)1536 * 512;             // [16384][512]
  unsigned short* Kb   = Qb + (size_t)16384 * 512;              // [16384][512]
  unsigned short* Vtb  = Kb + (size_t)16384 * 512;              // [8][512][2048]

  cast_kernel<<<8960, 256, 0, stream>>>(x, wq, wk, wv, xb, wcat);
  gemm_qkv<<<dim3(128, 12), 256, 0, stream>>>(xb, wcat, Qb, Kb, Vtb);
  hipFuncSetAttribute(reinterpret_cast<const void*>(flash_kernel),
                      hipFuncAttributeMaxDynamicSharedMemorySize, FL_SMEM);
  flash_kernel<<<256, 512, FL_SMEM, stream>>>(Qb, Kb, Vtb, out);
}